// Round 11
// baseline (161.185 us; speedup 1.0000x reference)
//
#include <hip/hip_runtime.h>
#include <hip/hip_fp16.h>

#define NB 64
#define NBUCKETS (NB * NB)   // 4096

typedef unsigned int uint2v __attribute__((ext_vector_type(2)));

__device__ __forceinline__ float sigm(float v)
{
    return 1.0f / (1.0f + __expf(0.3f - v));
}

__device__ __forceinline__ unsigned int q8(float s)
{
    // s in (0,1) strictly (sigmoid); round-to-nearest u8
    return (unsigned int)fmaf(s, 255.0f, 0.5f);
}

// ---------------------------------------------------------------------------
// Phase 1: sigmoid + transpose + u8 (y,z)-quad pack. 4 B/voxel.
// Q4[z][y][x] (x fastest), bytes: b0=s(x,y,z) b1=s(x,y+1,z)
//                                 b2=s(x,y,z+1) b3=s(x,y+1,z+1)
// y+1==256 / z+1==256 components baked to 0. One dwordx2 at (z,y,x) covers
// x..x+1 -> all 8 trilinear corners in one gather.
//
// DEPTH-2 register prefetch: two pending plane loads (register sets A/B,
// alternating by plane parity); a plane's load is consumed two iterations
// after issue, so ~2 full plane-workloads (ds_write+barrier+pack) of latency
// budget. 3-buffer LDS rotation -> one barrier per plane (writer of S[y%3]
// is separated from its last reader, pack(y+2), by the iter-(y+1) barrier).
// 16 y-planes per block: plane-read ratio 17/16, half the prologue stalls.
// Grid: 16 ygroups * 8 xt * 8 zt = 1024 blocks, 256 threads.
// ---------------------------------------------------------------------------
__global__ __launch_bounds__(256) void packq4_kernel(
    const float* __restrict__ dens, unsigned int* __restrict__ Q)
{
    __shared__ float S[3][33 * 33 + 1];
    int bid = blockIdx.x;
    int y0 = (bid & 15) * 16;
    int xt = ((bid >> 4) & 7) * 32;
    int zt = (bid >> 7) * 32;
    int tid = threadIdx.x;

    const int xr = tid >> 3;          // 0..31 : x row within tile
    const int zq = tid & 7;           // 0..7  : float4 covers z = zt+4*zq..+3
    const bool halo = (tid < 32);     // halo thread: z = zt+32, x row = tid
    const bool hin  = (zt + 32 < 256);

    float4 rA = make_float4(0.f, 0.f, 0.f, 0.f), rB = rA;
    float rhA = 0.0f, rhB = 0.0f;

    // issue loads for plane y into (r, rh); no wait here
    auto issue = [&](int y, float4& r, float& rh) {
        if (y < 256) {
            r = *reinterpret_cast<const float4*>(
                dens + (size_t)(xt + xr) * 65536 + (size_t)y * 256 + zt + 4 * zq);
            if (halo && hin)
                rh = dens[(size_t)(xt + tid) * 65536 + (size_t)y * 256 + zt + 32];
        }
    };

    // consume registers (waits) and publish plane y to LDS
    auto publish = [&](int y, float4& r, float& rh) {
        bool yin = (y < 256);
        float* Sp = S[y % 3];
        Sp[(4 * zq + 0) * 33 + xr] = yin ? sigm(r.x) : 0.0f;
        Sp[(4 * zq + 1) * 33 + xr] = yin ? sigm(r.y) : 0.0f;
        Sp[(4 * zq + 2) * 33 + xr] = yin ? sigm(r.z) : 0.0f;
        Sp[(4 * zq + 3) * 33 + xr] = yin ? sigm(r.w) : 0.0f;
        if (halo) Sp[32 * 33 + tid] = (yin && hin) ? sigm(rh) : 0.0f;
    };

    auto packw = [&](int y) {
        const float* S0 = S[y % 3];           // plane y
        const float* S1 = S[(y + 1) % 3];     // plane y+1
        int xo = tid & 31;
        int zb = tid >> 5;
        #pragma unroll
        for (int i = 0; i < 4; ++i) {
            int zo = zb + 8 * i;
            unsigned int q = q8(S0[zo * 33 + xo])
                           | (q8(S1[zo * 33 + xo]) << 8)
                           | (q8(S0[(zo + 1) * 33 + xo]) << 16)
                           | (q8(S1[(zo + 1) * 33 + xo]) << 24);
            Q[((zt + zo) << 16) | (y << 8) | (xt + xo)] = q;
        }
    };

    // ---- prologue: planes y0+16 (slot A, may be OOB) and y0+15 (slot B)
    issue(y0 + 16, rA, rhA);
    issue(y0 + 15, rB, rhB);
    publish(y0 + 16, rA, rhA);        // waits on A only
    issue(y0 + 14, rA, rhA);
    __syncthreads();

    // planes y0+15 .. y0 (16 planes, unrolled by 2: odd->B, even->A)
    for (int y = y0 + 15; y >= y0; y -= 2) {
        publish(y, rB, rhB);                   // waits on B (issued 2 planes ago)
        if (y - 2 >= y0) issue(y - 2, rB, rhB);
        __syncthreads();
        packw(y);

        publish(y - 1, rA, rhA);               // waits on A
        if (y - 3 >= y0) issue(y - 3, rA, rhA);
        __syncthreads();
        packw(y - 1);
    }
}

// ---------------------------------------------------------------------------
// Ray bucketing: Morton-interleaved 64x64 grid over detector (ty, tz)
// ---------------------------------------------------------------------------
__device__ __forceinline__ int ray_bucket(const float* __restrict__ target, int r)
{
    float ty = target[3 * r + 1];
    float tz = target[3 * r + 2];
    int bu = (int)((ty + 10.0f) * (NB / 260.0f));
    int bv = (int)((tz + 10.0f) * (NB / 260.0f));
    bu = min(max(bu, 0), NB - 1);
    bv = min(max(bv, 0), NB - 1);
    int m = 0;
    #pragma unroll
    for (int b = 0; b < 6; ++b)
        m |= (((bu >> b) & 1) << (2 * b)) | (((bv >> b) & 1) << (2 * b + 1));
    return m;
}

__global__ __launch_bounds__(256) void zero_kernel(int* __restrict__ p, int n)
{
    int i = blockIdx.x * 256 + threadIdx.x;
    if (i < n) p[i] = 0;
}

__global__ __launch_bounds__(256) void hist_kernel(
    const float* __restrict__ target, int* __restrict__ hist, int nrays)
{
    int r = blockIdx.x * 256 + threadIdx.x;
    if (r < nrays) atomicAdd(&hist[ray_bucket(target, r)], 1);
}

// single block, 256 threads, 16 buckets each: exclusive scan + cursor zero
__global__ __launch_bounds__(256) void scan_kernel(
    const int* __restrict__ hist, int* __restrict__ offs, int* __restrict__ cursor)
{
    __shared__ int part[256];
    int t = threadIdx.x;
    int v[16];
    int s = 0;
    #pragma unroll
    for (int i = 0; i < 16; ++i) {
        v[i] = hist[t * 16 + i];
        s += v[i];
    }
    part[t] = s;
    __syncthreads();
    for (int d = 1; d < 256; d <<= 1) {
        int add = (t >= d) ? part[t - d] : 0;
        __syncthreads();
        part[t] += add;
        __syncthreads();
    }
    int base = part[t] - s;
    #pragma unroll
    for (int i = 0; i < 16; ++i) {
        offs[t * 16 + i] = base;
        base += v[i];
        cursor[t * 16 + i] = 0;
    }
}

__global__ __launch_bounds__(256) void scatter_kernel(
    const float* __restrict__ target, const int* __restrict__ offs,
    int* __restrict__ cursor, int* __restrict__ perm, int nrays)
{
    int r = blockIdx.x * 256 + threadIdx.x;
    if (r >= nrays) return;
    int bkt = ray_bucket(target, r);
    int pos = offs[bkt] + atomicAdd(&cursor[bkt], 1);
    perm[pos] = r;
}

// ---------------------------------------------------------------------------
// Boundary fetch: corners (c[y,z], c[y+1,z], c[y,z+1], c[y+1,z+1]) at one x,
// in u8 units; zeros per map_coordinates(mode="constant") semantics.
// ---------------------------------------------------------------------------
__device__ __forceinline__ float4 fetchB(
    const unsigned int* __restrict__ Q, int x, int y, int z)
{
    if ((unsigned)x < 256u) {
        bool yin = (unsigned)y < 256u;
        bool zin = (unsigned)z < 256u;
        if (yin && zin) {
            unsigned int v = Q[(z << 16) | (y << 8) | x];
            return make_float4((float)(v & 255u), (float)((v >> 8) & 255u),
                               (float)((v >> 16) & 255u), (float)(v >> 24));
        }
        if (y == -1 && zin) {
            unsigned int v = Q[(z << 16) | x];
            return make_float4(0.0f, (float)(v & 255u),
                               0.0f, (float)((v >> 16) & 255u));
        }
        if (yin && z == -1) {
            unsigned int v = Q[(y << 8) | x];
            return make_float4(0.0f, 0.0f,
                               (float)(v & 255u), (float)((v >> 8) & 255u));
        }
        if (y == -1 && z == -1) {
            unsigned int v = Q[x];
            return make_float4(0.0f, 0.0f, 0.0f, (float)(v & 255u));
        }
    }
    return make_float4(0.0f, 0.0f, 0.0f, 0.0f);
}

// ---------------------------------------------------------------------------
// Phase 2: 8 rays x 8 sample-phases per wave; ONE dwordx2 gather per sample.
// ---------------------------------------------------------------------------
__global__ __launch_bounds__(256) void drr_kernel(
    const unsigned int* __restrict__ Q,
    const float*  __restrict__ source,
    const float*  __restrict__ target,
    const float*  __restrict__ affine,
    const int*    __restrict__ npts_ptr,
    const int*    __restrict__ perm,
    float*        __restrict__ out,
    int nrays)
{
    const int lane  = threadIdx.x & 63;
    const int sub   = lane >> 3;            // ray within wave (0..7)
    const int phase = lane & 7;             // sample phase (0..7)
    const int wave  = threadIdx.x >> 6;
    int slot = blockIdx.x * 32 + wave * 8 + sub;
    bool valid = (slot < nrays);
    if (slot >= nrays) slot = nrays - 1;
    const int ray = perm ? perm[slot] : slot;
    const int npts = *npts_ptr;

    // inverse affine (last row [0,0,0,1])
    float a00 = affine[0], a01 = affine[1], a02 = affine[2],  b0 = affine[3];
    float a10 = affine[4], a11 = affine[5], a12 = affine[6],  b1 = affine[7];
    float a20 = affine[8], a21 = affine[9], a22 = affine[10], b2 = affine[11];
    float det = a00 * (a11 * a22 - a12 * a21)
              - a01 * (a10 * a22 - a12 * a20)
              + a02 * (a10 * a21 - a11 * a20);
    float rdet = 1.0f / det;
    float i00 =  (a11 * a22 - a12 * a21) * rdet;
    float i01 = -(a01 * a22 - a02 * a21) * rdet;
    float i02 =  (a01 * a12 - a02 * a11) * rdet;
    float i10 = -(a10 * a22 - a12 * a20) * rdet;
    float i11 =  (a00 * a22 - a02 * a20) * rdet;
    float i12 = -(a00 * a12 - a02 * a10) * rdet;
    float i20 =  (a10 * a21 - a11 * a20) * rdet;
    float i21 = -(a00 * a21 - a01 * a20) * rdet;
    float i22 =  (a00 * a11 - a01 * a10) * rdet;
    float it0 = -(i00 * b0 + i01 * b1 + i02 * b2);
    float it1 = -(i10 * b0 + i11 * b1 + i12 * b2);
    float it2 = -(i20 * b0 + i21 * b1 + i22 * b2);

    float sx = source[3 * ray + 0], sy = source[3 * ray + 1], sz = source[3 * ray + 2];
    float tx = target[3 * ray + 0], ty = target[3 * ray + 1], tz = target[3 * ray + 2];
    float dwx = tx - sx, dwy = ty - sy, dwz = tz - sz;
    float rl = sqrtf(dwx * dwx + dwy * dwy + dwz * dwz);

    float vsx = i00 * sx + i01 * sy + i02 * sz + it0;
    float vsy = i10 * sx + i11 * sy + i12 * sz + it1;
    float vsz = i20 * sx + i21 * sy + i22 * sz + it2;
    float vtx = i00 * tx + i01 * ty + i02 * tz + it0;
    float vty = i10 * tx + i11 * ty + i12 * tz + it1;
    float vtz = i20 * tx + i21 * ty + i22 * tz + it2;
    float vdx = vtx - vsx, vdy = vty - vsy, vdz = vtz - vsz;

    // clip to alpha range where a sample can touch an in-bounds corner
    float lo = 0.0f, hi = 1.0f;
    {
        float s3v[3] = {vsx, vsy, vsz};
        float d3v[3] = {vdx, vdy, vdz};
        #pragma unroll
        for (int k = 0; k < 3; ++k) {
            if (fabsf(d3v[k]) > 1e-8f) {
                float a = (-1.0f - s3v[k]) / d3v[k];
                float b = (256.0f - s3v[k]) / d3v[k];
                lo = fmaxf(lo, fminf(a, b));
                hi = fminf(hi, fmaxf(a, b));
            } else if (s3v[k] <= -1.0f || s3v[k] >= 256.0f) {
                lo = 1.0f; hi = 0.0f;
            }
        }
    }
    const float stepN = (float)(npts > 1 ? npts - 1 : 1);
    int pstart = max(0, (int)floorf(lo * stepN) - 1);
    int pend   = min(npts - 1, (int)ceilf(hi * stepN) + 1);

    const float step = 1.0f / stepN;
    float acc = 0.0f;

    float al0 = (float)(pstart + phase) * step;
    float x = fmaf(al0, vdx, vsx);
    float y = fmaf(al0, vdy, vsy);
    float z = fmaf(al0, vdz, vsz);
    float d8x = 8.0f * step * vdx;
    float d8y = 8.0f * step * vdy;
    float d8z = 8.0f * step * vdz;

    #pragma unroll 4
    for (int p = pstart + phase; p <= pend; p += 8) {
        float fx = floorf(x), fy = floorf(y), fz = floorf(z);
        int ix = (int)fx, iy = (int)fy, iz = (int)fz;
        float wx = x - fx, wy = y - fy, wz = z - fz;
        x += d8x; y += d8y; z += d8z;

        float4 A, B;   // corners (yz, y1z, yz1, y1z1) at x and x+1, u8 units
        bool interior = ((unsigned)ix < 255u) & ((unsigned)iy < 256u) &
                        ((unsigned)iz < 256u);
        if (interior) {
            int idx = (iz << 16) | (iy << 8) | ix;
            uint2v v;
            __builtin_memcpy(&v, Q + idx, 8);   // dwordx2: x and x+1
            unsigned int va = v.x, vb = v.y;
            A = make_float4((float)(va & 255u), (float)((va >> 8) & 255u),
                            (float)((va >> 16) & 255u), (float)(va >> 24));
            B = make_float4((float)(vb & 255u), (float)((vb >> 8) & 255u),
                            (float)((vb >> 16) & 255u), (float)(vb >> 24));
        } else {
            A = fetchB(Q, ix,     iy, iz);
            B = fetchB(Q, ix + 1, iy, iz);
        }
        float ca = fmaf(wy, A.y - A.x, A.x);     // (x,   z)
        float cb = fmaf(wy, A.w - A.z, A.z);     // (x,   z+1)
        float e  = fmaf(wz, cb - ca, ca);        // x
        float cc = fmaf(wy, B.y - B.x, B.x);     // (x+1, z)
        float cd = fmaf(wy, B.w - B.z, B.z);     // (x+1, z+1)
        float f  = fmaf(wz, cd - cc, cc);        // x+1
        acc += fmaf(wx, f - e, e);
    }

    // segmented 8-lane reduction (8 rays per wave)
    #pragma unroll
    for (int off = 4; off > 0; off >>= 1)
        acc += __shfl_down(acc, off, 8);

    if (phase == 0 && valid)
        out[ray] = acc * rl / ((float)npts * 255.0f);
}

// ---------------------------------------------------------------------------
extern "C" void kernel_launch(void* const* d_in, const int* in_sizes, int n_in,
                              void* d_out, int out_size, void* d_ws, size_t ws_size,
                              hipStream_t stream)
{
    const float* dens   = (const float*)d_in[0];
    const float* source = (const float*)d_in[1];
    const float* target = (const float*)d_in[2];
    const float* affine = (const float*)d_in[3];
    const int*   npts   = (const int*)d_in[4];
    float* out = (float*)d_out;

    const int nvox  = in_sizes[0];          // 256^3
    const int nrays = in_sizes[1] / 3;      // B*N

    size_t qBytes    = ((size_t)nvox * 4 + 255) & ~(size_t)255;
    size_t sortBytes = (size_t)(3 * NBUCKETS + nrays) * sizeof(int);

    unsigned int* Q = (unsigned int*)d_ws;
    int* hist   = (int*)((char*)d_ws + qBytes);
    int* offs   = hist + NBUCKETS;
    int* cursor = offs + NBUCKETS;
    int* perm   = cursor + NBUCKETS;
    const bool srt = (ws_size >= qBytes + sortBytes);
    int* permArg = srt ? perm : nullptr;

    if (srt) {
        zero_kernel<<<(NBUCKETS + 255) / 256, 256, 0, stream>>>(hist, NBUCKETS);
        hist_kernel<<<(nrays + 255) / 256, 256, 0, stream>>>(target, hist, nrays);
        scan_kernel<<<1, 256, 0, stream>>>(hist, offs, cursor);
        scatter_kernel<<<(nrays + 255) / 256, 256, 0, stream>>>(target, offs, cursor, perm, nrays);
    }

    packq4_kernel<<<1024, 256, 0, stream>>>(dens, Q);

    // 32 rays per block (4 waves x 8 rays)
    drr_kernel<<<(nrays + 31) / 32, 256, 0, stream>>>(
        Q, source, target, affine, npts, permArg, out, nrays);
}

// Round 12
// 153.501 us; speedup vs baseline: 1.0501x; 1.0501x over previous
//
#include <hip/hip_runtime.h>
#include <hip/hip_fp16.h>

#define NB 64
#define NBUCKETS (NB * NB)   // 4096

typedef unsigned int uint2v __attribute__((ext_vector_type(2)));

__device__ __forceinline__ float sigm(float v)
{
    return 1.0f / (1.0f + __expf(0.3f - v));
}

__device__ __forceinline__ unsigned int q8(float s)
{
    // s in (0,1) strictly (sigmoid); round-to-nearest u8
    return (unsigned int)fmaf(s, 255.0f, 0.5f);
}

// ---------------------------------------------------------------------------
// Phase 1: sigmoid + transpose + u8 (y,z)-quad pack. 4 B/voxel.
// Q4[z][y][x] (x fastest), bytes: b0=s(x,y,z) b1=s(x,y+1,z)
//                                 b2=s(x,y,z+1) b3=s(x,y+1,z+1)
// y+1==256 / z+1==256 components baked to 0. One dwordx2 at (z,y,x) covers
// x..x+1 -> all 8 trilinear corners in one gather.
//
// Register-staged prefetch (depth 1 — depth 2 measured SLOWER, r11): global
// loads for plane y-1 are ISSUED (into registers, no wait) before the
// ds_write+barrier+compute of plane y; 4 blocks/CU supply the rest of the
// MLP. 3-buffer LDS rotation -> one barrier per plane (writer of S[y%3] is
// separated from its last reader, pack(y+2), by the iter-(y+1) barrier).
// Grid: 32 ygroups * 8 xt * 8 zt = 2048 blocks, 256 threads.
// ---------------------------------------------------------------------------
__global__ __launch_bounds__(256) void packq4_kernel(
    const float* __restrict__ dens, unsigned int* __restrict__ Q)
{
    __shared__ float S[3][33 * 33 + 1];
    int bid = blockIdx.x;
    int y0 = (bid & 31) * 8;
    int xt = ((bid >> 5) & 7) * 32;
    int zt = (bid >> 8) * 32;
    int tid = threadIdx.x;

    const int xr = tid >> 3;          // 0..31 : x row within tile
    const int zq = tid & 7;           // 0..7  : float4 covers z = zt+4*zq..+3
    const bool halo = (tid < 32);     // halo thread: z = zt+32, x row = tid
    const bool hin  = (zt + 32 < 256);

    float4 r = make_float4(0.f, 0.f, 0.f, 0.f);
    float rh = 0.0f;

    // issue loads for plane y into (r, rh); no wait here
    auto issue_load = [&](int y) {
        if (y < 256) {
            r = *reinterpret_cast<const float4*>(
                dens + (size_t)(xt + xr) * 65536 + (size_t)y * 256 + zt + 4 * zq);
            if (halo && hin)
                rh = dens[(size_t)(xt + tid) * 65536 + (size_t)y * 256 + zt + 32];
        }
    };

    // ---- prologue: plane y0+8 (may be OOB -> zeros), then issue y0+7
    issue_load(y0 + 8);
    {
        bool yin = (y0 + 8 < 256);
        float* Sp = S[(y0 + 8) % 3];
        Sp[(4 * zq + 0) * 33 + xr] = yin ? sigm(r.x) : 0.0f;
        Sp[(4 * zq + 1) * 33 + xr] = yin ? sigm(r.y) : 0.0f;
        Sp[(4 * zq + 2) * 33 + xr] = yin ? sigm(r.z) : 0.0f;
        Sp[(4 * zq + 3) * 33 + xr] = yin ? sigm(r.w) : 0.0f;
        if (halo) Sp[32 * 33 + tid] = (yin && hin) ? sigm(rh) : 0.0f;
    }
    issue_load(y0 + 7);

    for (int y = y0 + 7; y >= y0; --y) {
        // (1) consume registers (waits on the pending loads)
        float s0 = sigm(r.x), s1 = sigm(r.y), s2 = sigm(r.z), s3 = sigm(r.w);
        float sh = (halo && hin) ? sigm(rh) : 0.0f;

        // (2) issue next plane's loads (no wait; latency spans barrier+compute)
        if (y > y0) issue_load(y - 1);

        // (3) publish plane y to LDS
        float* Sp = S[y % 3];
        Sp[(4 * zq + 0) * 33 + xr] = s0;
        Sp[(4 * zq + 1) * 33 + xr] = s1;
        Sp[(4 * zq + 2) * 33 + xr] = s2;
        Sp[(4 * zq + 3) * 33 + xr] = s3;
        if (halo) Sp[32 * 33 + tid] = sh;

        // (4) single barrier per plane
        __syncthreads();

        // (5) pack + write plane y
        const float* S0 = Sp;                 // plane y
        const float* S1 = S[(y + 1) % 3];     // plane y+1
        int xo = tid & 31;
        int zb = tid >> 5;
        #pragma unroll
        for (int i = 0; i < 4; ++i) {
            int zo = zb + 8 * i;
            unsigned int q = q8(S0[zo * 33 + xo])
                           | (q8(S1[zo * 33 + xo]) << 8)
                           | (q8(S0[(zo + 1) * 33 + xo]) << 16)
                           | (q8(S1[(zo + 1) * 33 + xo]) << 24);
            Q[((zt + zo) << 16) | (y << 8) | (xt + xo)] = q;
        }
        // no trailing barrier: next iter writes S[(y-1)%3] == S[(y+2)%3],
        // whose last readers (iter y+1) are separated by this iter's barrier.
    }
}

// ---------------------------------------------------------------------------
// Ray bucketing: Morton-interleaved 64x64 grid over detector (ty, tz)
// ---------------------------------------------------------------------------
__device__ __forceinline__ int ray_bucket(const float* __restrict__ target, int r)
{
    float ty = target[3 * r + 1];
    float tz = target[3 * r + 2];
    int bu = (int)((ty + 10.0f) * (NB / 260.0f));
    int bv = (int)((tz + 10.0f) * (NB / 260.0f));
    bu = min(max(bu, 0), NB - 1);
    bv = min(max(bv, 0), NB - 1);
    int m = 0;
    #pragma unroll
    for (int b = 0; b < 6; ++b)
        m |= (((bu >> b) & 1) << (2 * b)) | (((bv >> b) & 1) << (2 * b + 1));
    return m;
}

__global__ __launch_bounds__(256) void zero_kernel(int* __restrict__ p, int n)
{
    int i = blockIdx.x * 256 + threadIdx.x;
    if (i < n) p[i] = 0;
}

__global__ __launch_bounds__(256) void hist_kernel(
    const float* __restrict__ target, int* __restrict__ hist, int nrays)
{
    int r = blockIdx.x * 256 + threadIdx.x;
    if (r < nrays) atomicAdd(&hist[ray_bucket(target, r)], 1);
}

// single block, 256 threads, 16 buckets each: exclusive scan + cursor zero
__global__ __launch_bounds__(256) void scan_kernel(
    const int* __restrict__ hist, int* __restrict__ offs, int* __restrict__ cursor)
{
    __shared__ int part[256];
    int t = threadIdx.x;
    int v[16];
    int s = 0;
    #pragma unroll
    for (int i = 0; i < 16; ++i) {
        v[i] = hist[t * 16 + i];
        s += v[i];
    }
    part[t] = s;
    __syncthreads();
    for (int d = 1; d < 256; d <<= 1) {
        int add = (t >= d) ? part[t - d] : 0;
        __syncthreads();
        part[t] += add;
        __syncthreads();
    }
    int base = part[t] - s;
    #pragma unroll
    for (int i = 0; i < 16; ++i) {
        offs[t * 16 + i] = base;
        base += v[i];
        cursor[t * 16 + i] = 0;
    }
}

__global__ __launch_bounds__(256) void scatter_kernel(
    const float* __restrict__ target, const int* __restrict__ offs,
    int* __restrict__ cursor, int* __restrict__ perm, int nrays)
{
    int r = blockIdx.x * 256 + threadIdx.x;
    if (r >= nrays) return;
    int bkt = ray_bucket(target, r);
    int pos = offs[bkt] + atomicAdd(&cursor[bkt], 1);
    perm[pos] = r;
}

// ---------------------------------------------------------------------------
// Boundary fetch: corners (c[y,z], c[y+1,z], c[y,z+1], c[y+1,z+1]) at one x,
// in u8 units; zeros per map_coordinates(mode="constant") semantics.
// ---------------------------------------------------------------------------
__device__ __forceinline__ float4 fetchB(
    const unsigned int* __restrict__ Q, int x, int y, int z)
{
    if ((unsigned)x < 256u) {
        bool yin = (unsigned)y < 256u;
        bool zin = (unsigned)z < 256u;
        if (yin && zin) {
            unsigned int v = Q[(z << 16) | (y << 8) | x];
            return make_float4((float)(v & 255u), (float)((v >> 8) & 255u),
                               (float)((v >> 16) & 255u), (float)(v >> 24));
        }
        if (y == -1 && zin) {
            unsigned int v = Q[(z << 16) | x];
            return make_float4(0.0f, (float)(v & 255u),
                               0.0f, (float)((v >> 16) & 255u));
        }
        if (yin && z == -1) {
            unsigned int v = Q[(y << 8) | x];
            return make_float4(0.0f, 0.0f,
                               (float)(v & 255u), (float)((v >> 8) & 255u));
        }
        if (y == -1 && z == -1) {
            unsigned int v = Q[x];
            return make_float4(0.0f, 0.0f, 0.0f, (float)(v & 255u));
        }
    }
    return make_float4(0.0f, 0.0f, 0.0f, 0.0f);
}

// ---------------------------------------------------------------------------
// Phase 2: 8 rays x 8 sample-phases per wave; ONE dwordx2 gather per sample.
// ---------------------------------------------------------------------------
__global__ __launch_bounds__(256) void drr_kernel(
    const unsigned int* __restrict__ Q,
    const float*  __restrict__ source,
    const float*  __restrict__ target,
    const float*  __restrict__ affine,
    const int*    __restrict__ npts_ptr,
    const int*    __restrict__ perm,
    float*        __restrict__ out,
    int nrays)
{
    const int lane  = threadIdx.x & 63;
    const int sub   = lane >> 3;            // ray within wave (0..7)
    const int phase = lane & 7;             // sample phase (0..7)
    const int wave  = threadIdx.x >> 6;
    int slot = blockIdx.x * 32 + wave * 8 + sub;
    bool valid = (slot < nrays);
    if (slot >= nrays) slot = nrays - 1;
    const int ray = perm ? perm[slot] : slot;
    const int npts = *npts_ptr;

    // inverse affine (last row [0,0,0,1])
    float a00 = affine[0], a01 = affine[1], a02 = affine[2],  b0 = affine[3];
    float a10 = affine[4], a11 = affine[5], a12 = affine[6],  b1 = affine[7];
    float a20 = affine[8], a21 = affine[9], a22 = affine[10], b2 = affine[11];
    float det = a00 * (a11 * a22 - a12 * a21)
              - a01 * (a10 * a22 - a12 * a20)
              + a02 * (a10 * a21 - a11 * a20);
    float rdet = 1.0f / det;
    float i00 =  (a11 * a22 - a12 * a21) * rdet;
    float i01 = -(a01 * a22 - a02 * a21) * rdet;
    float i02 =  (a01 * a12 - a02 * a11) * rdet;
    float i10 = -(a10 * a22 - a12 * a20) * rdet;
    float i11 =  (a00 * a22 - a02 * a20) * rdet;
    float i12 = -(a00 * a12 - a02 * a10) * rdet;
    float i20 =  (a10 * a21 - a11 * a20) * rdet;
    float i21 = -(a00 * a21 - a01 * a20) * rdet;
    float i22 =  (a00 * a11 - a01 * a10) * rdet;
    float it0 = -(i00 * b0 + i01 * b1 + i02 * b2);
    float it1 = -(i10 * b0 + i11 * b1 + i12 * b2);
    float it2 = -(i20 * b0 + i21 * b1 + i22 * b2);

    float sx = source[3 * ray + 0], sy = source[3 * ray + 1], sz = source[3 * ray + 2];
    float tx = target[3 * ray + 0], ty = target[3 * ray + 1], tz = target[3 * ray + 2];
    float dwx = tx - sx, dwy = ty - sy, dwz = tz - sz;
    float rl = sqrtf(dwx * dwx + dwy * dwy + dwz * dwz);

    float vsx = i00 * sx + i01 * sy + i02 * sz + it0;
    float vsy = i10 * sx + i11 * sy + i12 * sz + it1;
    float vsz = i20 * sx + i21 * sy + i22 * sz + it2;
    float vtx = i00 * tx + i01 * ty + i02 * tz + it0;
    float vty = i10 * tx + i11 * ty + i12 * tz + it1;
    float vtz = i20 * tx + i21 * ty + i22 * tz + it2;
    float vdx = vtx - vsx, vdy = vty - vsy, vdz = vtz - vsz;

    // clip to alpha range where a sample can touch an in-bounds corner
    float lo = 0.0f, hi = 1.0f;
    {
        float s3v[3] = {vsx, vsy, vsz};
        float d3v[3] = {vdx, vdy, vdz};
        #pragma unroll
        for (int k = 0; k < 3; ++k) {
            if (fabsf(d3v[k]) > 1e-8f) {
                float a = (-1.0f - s3v[k]) / d3v[k];
                float b = (256.0f - s3v[k]) / d3v[k];
                lo = fmaxf(lo, fminf(a, b));
                hi = fminf(hi, fmaxf(a, b));
            } else if (s3v[k] <= -1.0f || s3v[k] >= 256.0f) {
                lo = 1.0f; hi = 0.0f;
            }
        }
    }
    const float stepN = (float)(npts > 1 ? npts - 1 : 1);
    int pstart = max(0, (int)floorf(lo * stepN) - 1);
    int pend   = min(npts - 1, (int)ceilf(hi * stepN) + 1);

    const float step = 1.0f / stepN;
    float acc = 0.0f;

    float al0 = (float)(pstart + phase) * step;
    float x = fmaf(al0, vdx, vsx);
    float y = fmaf(al0, vdy, vsy);
    float z = fmaf(al0, vdz, vsz);
    float d8x = 8.0f * step * vdx;
    float d8y = 8.0f * step * vdy;
    float d8z = 8.0f * step * vdz;

    #pragma unroll 4
    for (int p = pstart + phase; p <= pend; p += 8) {
        float fx = floorf(x), fy = floorf(y), fz = floorf(z);
        int ix = (int)fx, iy = (int)fy, iz = (int)fz;
        float wx = x - fx, wy = y - fy, wz = z - fz;
        x += d8x; y += d8y; z += d8z;

        float4 A, B;   // corners (yz, y1z, yz1, y1z1) at x and x+1, u8 units
        bool interior = ((unsigned)ix < 255u) & ((unsigned)iy < 256u) &
                        ((unsigned)iz < 256u);
        if (interior) {
            int idx = (iz << 16) | (iy << 8) | ix;
            uint2v v;
            __builtin_memcpy(&v, Q + idx, 8);   // dwordx2: x and x+1
            unsigned int va = v.x, vb = v.y;
            A = make_float4((float)(va & 255u), (float)((va >> 8) & 255u),
                            (float)((va >> 16) & 255u), (float)(va >> 24));
            B = make_float4((float)(vb & 255u), (float)((vb >> 8) & 255u),
                            (float)((vb >> 16) & 255u), (float)(vb >> 24));
        } else {
            A = fetchB(Q, ix,     iy, iz);
            B = fetchB(Q, ix + 1, iy, iz);
        }
        float ca = fmaf(wy, A.y - A.x, A.x);     // (x,   z)
        float cb = fmaf(wy, A.w - A.z, A.z);     // (x,   z+1)
        float e  = fmaf(wz, cb - ca, ca);        // x
        float cc = fmaf(wy, B.y - B.x, B.x);     // (x+1, z)
        float cd = fmaf(wy, B.w - B.z, B.z);     // (x+1, z+1)
        float f  = fmaf(wz, cd - cc, cc);        // x+1
        acc += fmaf(wx, f - e, e);
    }

    // segmented 8-lane reduction (8 rays per wave)
    #pragma unroll
    for (int off = 4; off > 0; off >>= 1)
        acc += __shfl_down(acc, off, 8);

    if (phase == 0 && valid)
        out[ray] = acc * rl / ((float)npts * 255.0f);
}

// ---------------------------------------------------------------------------
extern "C" void kernel_launch(void* const* d_in, const int* in_sizes, int n_in,
                              void* d_out, int out_size, void* d_ws, size_t ws_size,
                              hipStream_t stream)
{
    const float* dens   = (const float*)d_in[0];
    const float* source = (const float*)d_in[1];
    const float* target = (const float*)d_in[2];
    const float* affine = (const float*)d_in[3];
    const int*   npts   = (const int*)d_in[4];
    float* out = (float*)d_out;

    const int nvox  = in_sizes[0];          // 256^3
    const int nrays = in_sizes[1] / 3;      // B*N

    size_t qBytes    = ((size_t)nvox * 4 + 255) & ~(size_t)255;
    size_t sortBytes = (size_t)(3 * NBUCKETS + nrays) * sizeof(int);

    unsigned int* Q = (unsigned int*)d_ws;
    int* hist   = (int*)((char*)d_ws + qBytes);
    int* offs   = hist + NBUCKETS;
    int* cursor = offs + NBUCKETS;
    int* perm   = cursor + NBUCKETS;
    const bool srt = (ws_size >= qBytes + sortBytes);
    int* permArg = srt ? perm : nullptr;

    if (srt) {
        zero_kernel<<<(NBUCKETS + 255) / 256, 256, 0, stream>>>(hist, NBUCKETS);
        hist_kernel<<<(nrays + 255) / 256, 256, 0, stream>>>(target, hist, nrays);
        scan_kernel<<<1, 256, 0, stream>>>(hist, offs, cursor);
        scatter_kernel<<<(nrays + 255) / 256, 256, 0, stream>>>(target, offs, cursor, perm, nrays);
    }

    packq4_kernel<<<2048, 256, 0, stream>>>(dens, Q);

    // 32 rays per block (4 waves x 8 rays)
    drr_kernel<<<(nrays + 31) / 32, 256, 0, stream>>>(
        Q, source, target, affine, npts, permArg, out, nrays);
}